// Round 7
// baseline (362.342 us; speedup 1.0000x reference)
//
#include <hip/hip_runtime.h>

// R7 design (delta vs R6):
//  - NEW prepack pass: reads W (f32) + mask with fully row-contiguous bursts,
//    fuses mask into sign (masked -> bf16 -1.0), writes tile-ordered packed
//    bf16 where each 32-col j-tile is 1KB contiguous in per-lane fragment
//    order. Rationale: 5 rounds pinned at ~1.6-1.8 TB/s FETCH because every
//    access pattern advanced q-row streams in 128B granules across 9KB-strided
//    pages; harness fillBuffer proves 6.47 TB/s on linear streams (and shows
//    ws ~1.36GB). Prepack makes 2/3 of all traffic linear.
//  - attn: W+M = ONE 16B/lane (1KB/wave contiguous) load per tile, no LDS,
//    mode-independent; 3-slot register rotation; K/V register loads (L2-hot).
//  - chunked x3: packed buffer (56MB) reused per chunk; attn reads L3-hot.
//  keeps: swapped QK^T, no-max softmax (masked -> exactly 0), split-K=3 +
//  plain-sum combine, QKV/out projection kernels, dual-mode prepack via
//  early-exit template instances.

typedef __attribute__((ext_vector_type(8))) short bf16x8;
typedef __attribute__((ext_vector_type(4))) short bf16x4;
typedef __attribute__((ext_vector_type(4))) float f32x4;
typedef __attribute__((ext_vector_type(4))) unsigned int u32x4;

constexpr int B_  = 2;
constexpr int H_  = 8;
constexpr int NQ_ = 2304;
constexpr int DM_ = 64;
constexpr int DK_ = 32;
constexpr int NT_ = NQ_ / 32;     // 72 j-tiles of 32
constexpr int CH_ = 3;            // split-K chunks
constexpr int TPC_ = NT_ / CH_;   // 24 tiles per chunk
constexpr int GT_ = B_ * H_ * (NQ_ / 16);  // 2304 i-tiles total
constexpr float SCALE_ = 0.17677669529663687f;  // 1/sqrt(32)

// ws layout (bytes)
constexpr size_t OFF_Q    = 0;
constexpr size_t OFF_K    = 2359296;
constexpr size_t OFF_V    = 4718592;
constexpr size_t OFF_OMID = 7077888;    // 2*2304*256 f32
constexpr size_t OFF_FLAG = 11796480;
constexpr size_t OFF_OP   = 11796736;   // CH*2304*512 f32
constexpr size_t OFF_ML   = 25952512;   // CH*2304*32  f32
constexpr size_t OFF_PK   = 26837248;   // packed: 2304*24*512 u16 = 56.6MB

static __device__ __forceinline__ unsigned short f2bf(float f) {
    unsigned int u = __builtin_bit_cast(unsigned int, f);
    u += 0x7fffu + ((u >> 16) & 1u);          // RNE; inputs here are finite
    return (unsigned short)(u >> 16);
}
static __device__ __forceinline__ float bf2f(short s) {
    return __builtin_bit_cast(float, ((unsigned int)(unsigned short)s) << 16);
}

// ---------------- k0: mask dtype detect ----------------
__global__ void detect_mask_k(const unsigned int* __restrict__ m, int* __restrict__ flag) {
    int t = threadIdx.x;                       // 64 threads, 1 wave
    unsigned int v = 0;
    for (int k = 0; k < 16; ++k) v |= m[t * 16 + k];   // first 4KB, safe in both modes
    unsigned long long b = __ballot(v > 1u);
    if (t == 0) *flag = (b != 0ull) ? 1 : 0;   // 1 => byte-packed bools
}

// ---------------- k1: QKV projections ----------------
__global__ __launch_bounds__(256) void proj_qkv_k(
    const float* __restrict__ qin, const float* __restrict__ kin, const float* __restrict__ vin,
    const float* __restrict__ Wq, const float* __restrict__ bq,
    const float* __restrict__ Wk, const float* __restrict__ bk,
    const float* __restrict__ Wv, const float* __restrict__ bv,
    unsigned short* __restrict__ Qbf, unsigned short* __restrict__ Kbf,
    unsigned short* __restrict__ Vbf)
{
    const int sel = blockIdx.y;
    const float* in  = sel == 0 ? qin : (sel == 1 ? kin : vin);
    const float* W   = sel == 0 ? Wq  : (sel == 1 ? Wk  : Wv);
    const float* bia = sel == 0 ? bq  : (sel == 1 ? bk  : bv);

    const int rt = blockIdx.x;                 // 0..(B*NQ/8-1)
    const int b  = rt / (NQ_ / 8);
    const int r0 = (rt % (NQ_ / 8)) * 8;

    __shared__ alignas(16) float ins[8][64];
    const int t = threadIdx.x;
    const float4* src = reinterpret_cast<const float4*>(in + ((size_t)b * NQ_ + r0) * DM_);
    if (t < 128) reinterpret_cast<float4*>(&ins[0][0])[t] = src[t];
    __syncthreads();

    float acc[8];
#pragma unroll
    for (int r = 0; r < 8; ++r) acc[r] = 0.f;
    const float* wrow = W + t * DM_;
    for (int m = 0; m < DM_; ++m) {
        float wv = wrow[m];
#pragma unroll
        for (int r = 0; r < 8; ++r) acc[r] += ins[r][m] * wv;
    }
    const float bb = bia[t];
    const int h = t >> 5, d = t & 31;
#pragma unroll
    for (int r = 0; r < 8; ++r) {
        float o = acc[r] + bb;
        if (sel == 0) o *= SCALE_;             // fold 1/sqrt(dk) into Q
        unsigned short bvv = f2bf(o);
        if (sel == 2) Vbf[(((size_t)b * H_ + h) * DK_ + d) * NQ_ + (r0 + r)] = bvv;
        else {
            unsigned short* out = (sel == 1) ? Kbf : Qbf;
            out[(((size_t)b * H_ + h) * NQ_ + (r0 + r)) * DK_ + d] = bvv;
        }
    }
}

// ---------------- k1b: prepack weights+mask (linear-burst reads) ----------------
// packed layout: [g=bh*144+it][tloc 0..23][lane 0..63] x 16B, where lane
// (l15,hi)'s 16B = { W[i0+l15][j0+4hi .. +3], W[i0+l15][j0+16+4hi .. +3] } as
// bf16 with sign = mask (masked -> -1.0).
template<bool ISBYTE>
static __device__ __forceinline__ void prepack_body(
    const float* __restrict__ attw, const unsigned char* __restrict__ maskb,
    const int* __restrict__ flagp, unsigned short* __restrict__ packed, int chunk)
{
    if (((*flagp) != 0) != ISBYTE) return;

    const int g = blockIdx.x;                  // 0..2303
    const int bh = g / 144, it = g % 144;
    const int i0 = it * 16;
    const int t = threadIdx.x;

    __shared__ float Wl[16][260];
    __shared__ int   Ml[16][260];

    const size_t rowbase = ((size_t)bh * NQ_ + i0) * NQ_;
    const int cchunk = chunk * (TPC_ * 32);    // 768
    unsigned short* pout = packed + (size_t)g * (TPC_ * 512);

    for (int sp = 0; sp < 3; ++sp) {
        const int c0 = cchunk + sp * 256;
        // ---- load 16 rows x 256 cols, fully row-contiguous ----
#pragma unroll
        for (int k = 0; k < 4; ++k) {
            const int i = t + k * 256;         // 0..1023
            const int row = i >> 6, c4 = (i & 63) * 4;
            const size_t goff = rowbase + (size_t)row * NQ_ + c0 + c4;
            float4 wv = *reinterpret_cast<const float4*>(attw + goff);
            *reinterpret_cast<float4*>(&Wl[row][c4]) = wv;
            if constexpr (ISBYTE) {
                uchar4 mv = *reinterpret_cast<const uchar4*>(maskb + goff);
                int4 mi = {mv.x, mv.y, mv.z, mv.w};
                *reinterpret_cast<int4*>(&Ml[row][c4]) = mi;
            } else {
                int4 mi = *reinterpret_cast<const int4*>((const int*)maskb + goff);
                *reinterpret_cast<int4*>(&Ml[row][c4]) = mi;
            }
        }
        __syncthreads();
        // ---- gather to tile-order, write linear ----
#pragma unroll
        for (int sidx = 0; sidx < 2; ++sidx) {
            const int s = t + sidx * 256;      // 0..511
            const int jloc = s >> 6, l = s & 63;
            const int l15 = l & 15, hi = l >> 4;
            const int cb = jloc * 32 + 4 * hi;
            unsigned short u[8];
#pragma unroll
            for (int i2 = 0; i2 < 4; ++i2) {
                u[i2]     = Ml[l15][cb + i2]      ? (unsigned short)0xBF80u : f2bf(Wl[l15][cb + i2]);
                u[4 + i2] = Ml[l15][cb + 16 + i2] ? (unsigned short)0xBF80u : f2bf(Wl[l15][cb + 16 + i2]);
            }
            u32x4 o;
#pragma unroll
            for (int k = 0; k < 4; ++k)
                o[k] = (unsigned int)u[2 * k] | ((unsigned int)u[2 * k + 1] << 16);
            *reinterpret_cast<u32x4*>(pout + ((size_t)(sp * 8 + jloc)) * 512 + l * 8) = o;
        }
        __syncthreads();
    }
}

__global__ __launch_bounds__(256) void prepack_byte_k(
    const float* __restrict__ attw, const unsigned char* __restrict__ maskb,
    const int* __restrict__ flagp, unsigned short* __restrict__ packed, int chunk)
{ prepack_body<true>(attw, maskb, flagp, packed, chunk); }

__global__ __launch_bounds__(256) void prepack_int_k(
    const float* __restrict__ attw, const unsigned char* __restrict__ maskb,
    const int* __restrict__ flagp, unsigned short* __restrict__ packed, int chunk)
{ prepack_body<false>(attw, maskb, flagp, packed, chunk); }

// ---------------- k2: flash attention (packed stream, 3-slot rotation) ----------
struct Slot {
    bf16x8 wm;                  // packed weight+mask fragment
    bf16x8 ka0, ka1;            // K A-fragments
    bf16x4 v00, v01, v10, v11;  // V B-fragment halves
};

static __device__ __forceinline__ void issue_slot(
    Slot& s, const unsigned short* __restrict__ pwm,
    const unsigned short* __restrict__ kbase, const unsigned short* __restrict__ vbase,
    int u, int j0base, int lane, int l15, int hi)
{
    const int j0 = j0base + u * 32;
    s.wm  = *reinterpret_cast<const bf16x8*>(pwm + (size_t)u * 512 + lane * 8);
    s.ka0 = *reinterpret_cast<const bf16x8*>(kbase + (size_t)(j0 + l15) * DK_ + 8 * hi);
    s.ka1 = *reinterpret_cast<const bf16x8*>(kbase + (size_t)(j0 + 16 + l15) * DK_ + 8 * hi);
    s.v00 = *reinterpret_cast<const bf16x4*>(vbase + (size_t)l15 * NQ_ + j0 + 4 * hi);
    s.v01 = *reinterpret_cast<const bf16x4*>(vbase + (size_t)l15 * NQ_ + j0 + 16 + 4 * hi);
    s.v10 = *reinterpret_cast<const bf16x4*>(vbase + (size_t)(16 + l15) * NQ_ + j0 + 4 * hi);
    s.v11 = *reinterpret_cast<const bf16x4*>(vbase + (size_t)(16 + l15) * NQ_ + j0 + 16 + 4 * hi);
}

static __device__ __forceinline__ void consume_slot(
    const Slot& s, bf16x8 qb, f32x4& oacc0, f32x4& oacc1, float& lrun)
{
    const f32x4 zero = {0.f, 0.f, 0.f, 0.f};
    f32x4 s0 = __builtin_amdgcn_mfma_f32_16x16x32_bf16(s.ka0, qb, zero, 0, 0, 0);
    f32x4 s1 = __builtin_amdgcn_mfma_f32_16x16x32_bf16(s.ka1, qb, zero, 0, 0, 0);

    float p0[4], p1[4];
#pragma unroll
    for (int r = 0; r < 4; ++r) {
        float w0f = bf2f(s.wm[r]);
        float w1f = bf2f(s.wm[4 + r]);
        float e0 = __expf(s0[r] * w0f);
        float e1 = __expf(s1[r] * w1f);
        p0[r] = (w0f < 0.f) ? 0.f : e0;        // masked encoded as negative
        p1[r] = (w1f < 0.f) ? 0.f : e1;
    }
    lrun += ((p0[0] + p0[1]) + (p0[2] + p0[3])) + ((p1[0] + p1[1]) + (p1[2] + p1[3]));

    bf16x8 pa;
#pragma unroll
    for (int r = 0; r < 4; ++r) {
        pa[r]     = (short)f2bf(p0[r]);
        pa[4 + r] = (short)f2bf(p1[r]);
    }
    bf16x8 vb0 = __builtin_shufflevector(s.v00, s.v01, 0, 1, 2, 3, 4, 5, 6, 7);
    bf16x8 vb1 = __builtin_shufflevector(s.v10, s.v11, 0, 1, 2, 3, 4, 5, 6, 7);
    oacc0 = __builtin_amdgcn_mfma_f32_16x16x32_bf16(pa, vb0, oacc0, 0, 0, 0);
    oacc1 = __builtin_amdgcn_mfma_f32_16x16x32_bf16(pa, vb1, oacc1, 0, 0, 0);
}

__global__ __launch_bounds__(256) void attn_k(
    const unsigned short* __restrict__ Qbf,
    const unsigned short* __restrict__ Kbf,
    const unsigned short* __restrict__ Vbf,
    const unsigned short* __restrict__ packed,
    float* __restrict__ Opart,
    float* __restrict__ MLpart,
    int chunk)
{
    const int lane = threadIdx.x & 63;
    const int l15 = lane & 15, hi = lane >> 4;
    const int g = blockIdx.x * 4 + (threadIdx.x >> 6);   // i-tile id 0..2303
    const int bh = g / (NQ_ / 16);
    const int it = g % (NQ_ / 16);
    const int i0 = it * 16;

    const unsigned short* qbase = Qbf + (size_t)bh * NQ_ * DK_;
    const unsigned short* kbase = Kbf + (size_t)bh * NQ_ * DK_;
    const unsigned short* vbase = Vbf + (size_t)bh * DK_ * NQ_;
    const unsigned short* pwm   = packed + (size_t)g * (TPC_ * 512);

    const int q = i0 + l15;                    // this lane's q-row
    bf16x8 qb = *reinterpret_cast<const bf16x8*>(qbase + (size_t)q * DK_ + 8 * hi);

    const int j0base = chunk * TPC_ * 32;

    f32x4 oacc0 = {0.f, 0.f, 0.f, 0.f}, oacc1 = {0.f, 0.f, 0.f, 0.f};
    float lrun = 0.f;

    Slot sl0, sl1, sl2;
    issue_slot(sl0, pwm, kbase, vbase, 0, j0base, lane, l15, hi);
    issue_slot(sl1, pwm, kbase, vbase, 1, j0base, lane, l15, hi);
    issue_slot(sl2, pwm, kbase, vbase, 2, j0base, lane, l15, hi);

    for (int u = 0; u < TPC_; u += 3) {
        consume_slot(sl0, qb, oacc0, oacc1, lrun);
        if (u + 3 < TPC_) issue_slot(sl0, pwm, kbase, vbase, u + 3, j0base, lane, l15, hi);
        consume_slot(sl1, qb, oacc0, oacc1, lrun);
        if (u + 4 < TPC_) issue_slot(sl1, pwm, kbase, vbase, u + 4, j0base, lane, l15, hi);
        consume_slot(sl2, qb, oacc0, oacc1, lrun);
        if (u + 5 < TPC_) issue_slot(sl2, pwm, kbase, vbase, u + 5, j0base, lane, l15, hi);
    }

    float* op = Opart + ((size_t)chunk * GT_ + g) * 512;
#pragma unroll
    for (int r = 0; r < 4; ++r) {
        op[(4 * hi + r) * 32 + l15]      = oacc0[r];
        op[(4 * hi + r) * 32 + 16 + l15] = oacc1[r];
    }
    lrun += __shfl_xor(lrun, 16, 64);
    lrun += __shfl_xor(lrun, 32, 64);
    if (hi == 0) {
        float* mlp = MLpart + ((size_t)chunk * GT_ + g) * 32;
        mlp[l15] = lrun;
    }
}

// ---------------- k2b: combine split-K partials (plain sum) ----------------
__global__ __launch_bounds__(64) void combine_k(
    const float* __restrict__ Opart, const float* __restrict__ MLpart,
    float* __restrict__ Omid)
{
    const int g = blockIdx.x;                  // i-tile id
    const int lane = threadIdx.x;
    const int row = lane >> 2;                 // 16 rows
    const int c4  = (lane & 3) * 8;            // 8 dv per lane
    const int bh = g / (NQ_ / 16);
    const int it = g % (NQ_ / 16);
    const int b = bh / H_, h = bh % H_;

    float lg = 0.f;
#pragma unroll
    for (int c = 0; c < CH_; ++c)
        lg += MLpart[((size_t)c * GT_ + g) * 32 + row];
    float inv = 1.0f / lg;

    const size_t ob = (size_t)row * 32 + c4;
    f32x4 a0 = {0.f,0.f,0.f,0.f}, a1 = {0.f,0.f,0.f,0.f};
#pragma unroll
    for (int c = 0; c < CH_; ++c) {
        const float* opp = Opart + ((size_t)c * GT_ + g) * 512 + ob;
        a0 += *reinterpret_cast<const f32x4*>(opp);
        a1 += *reinterpret_cast<const f32x4*>(opp + 4);
    }
    a0 *= inv; a1 *= inv;
    float* dst = Omid + ((size_t)b * NQ_ + it * 16 + row) * 256 + h * 32 + c4;
    *reinterpret_cast<f32x4*>(dst)     = a0;
    *reinterpret_cast<f32x4*>(dst + 4) = a1;
}

// ---------------- k3: output projection ----------------
__global__ __launch_bounds__(256) void proj_out_k(
    const float* __restrict__ Omid, const float* __restrict__ Wo,
    const float* __restrict__ bo, float* __restrict__ out)
{
    const int rt = blockIdx.x;                 // 0..(B*NQ/16-1)
    const int b  = rt / (NQ_ / 16);
    const int r0 = (rt % (NQ_ / 16)) * 16;

    __shared__ alignas(16) float lds[16][256]; // 16KB
    const int t = threadIdx.x;
    const float4* src = reinterpret_cast<const float4*>(Omid + ((size_t)b * NQ_ + r0) * 256);
#pragma unroll
    for (int k = 0; k < 4; ++k) reinterpret_cast<float4*>(&lds[0][0])[t + k * 256] = src[t + k * 256];
    __syncthreads();

    const int m = t & 63, rg = t >> 6;
    float acc[4] = {0.f, 0.f, 0.f, 0.f};
    const float* wrow = Wo + m * 256;
    for (int c = 0; c < 256; ++c) {
        float wv = wrow[c];
#pragma unroll
        for (int rr = 0; rr < 4; ++rr) acc[rr] += lds[rg * 4 + rr][c] * wv;
    }
    const float bb = bo[m];
#pragma unroll
    for (int rr = 0; rr < 4; ++rr)
        out[((size_t)b * NQ_ + r0 + rg * 4 + rr) * 64 + m] = acc[rr] + bb;
}

extern "C" void kernel_launch(void* const* d_in, const int* in_sizes, int n_in,
                              void* d_out, int out_size, void* d_ws, size_t ws_size,
                              hipStream_t stream)
{
    (void)in_sizes; (void)n_in; (void)out_size; (void)ws_size;
    const float* qin  = (const float*)d_in[0];
    const float* kin  = (const float*)d_in[1];
    const float* vin  = (const float*)d_in[2];
    const float* attw = (const float*)d_in[3];
    const void*  mask = d_in[4];
    const float* Wq = (const float*)d_in[5];
    const float* bq = (const float*)d_in[6];
    const float* Wk = (const float*)d_in[7];
    const float* bk = (const float*)d_in[8];
    const float* Wv = (const float*)d_in[9];
    const float* bv = (const float*)d_in[10];
    const float* Wo = (const float*)d_in[11];
    const float* bo = (const float*)d_in[12];

    char* ws = (char*)d_ws;
    unsigned short* Qbf   = (unsigned short*)(ws + OFF_Q);
    unsigned short* Kbf   = (unsigned short*)(ws + OFF_K);
    unsigned short* Vbf   = (unsigned short*)(ws + OFF_V);
    float*          Omid  = (float*)(ws + OFF_OMID);
    int*            flag  = (int*)(ws + OFF_FLAG);
    float*          Opart = (float*)(ws + OFF_OP);
    float*          MLp   = (float*)(ws + OFF_ML);
    unsigned short* Pk    = (unsigned short*)(ws + OFF_PK);

    detect_mask_k<<<1, 64, 0, stream>>>((const unsigned int*)mask, flag);
    proj_qkv_k<<<dim3(B_ * NQ_ / 8, 3), 256, 0, stream>>>(
        qin, kin, vin, Wq, bq, Wk, bk, Wv, bv, Qbf, Kbf, Vbf);
    for (int c = 0; c < CH_; ++c) {
        prepack_byte_k<<<GT_, 256, 0, stream>>>(
            attw, (const unsigned char*)mask, flag, Pk, c);
        prepack_int_k<<<GT_, 256, 0, stream>>>(
            attw, (const unsigned char*)mask, flag, Pk, c);
        attn_k<<<GT_ / 4, 256, 0, stream>>>(Qbf, Kbf, Vbf, Pk, Opart, MLp, c);
    }
    combine_k<<<GT_, 64, 0, stream>>>(Opart, MLp, Omid);
    proj_out_k<<<B_ * NQ_ / 16, 256, 0, stream>>>(Omid, Wo, bo, (float*)d_out);
}

// Round 8
// 251.309 us; speedup vs baseline: 1.4418x; 1.4418x over previous
//
#include <hip/hip_runtime.h>

// R8 design (delta vs R6/R7):
//  - attn stages its W+M chunk-panel (16 rows x 768 cols) with 3KB-per-row
//    sequential bursts (3 consecutive 1KB wave loads per row per array),
//    fusing mask into bf16 sign, into a 24KB XOR-swizzled LDS panel.
//    Burst-length theory: 128B/row-visit -> 1.6TB/s (R2-R6), ~1KB -> ~2.5
//    (R7 prepack), linear -> 6.9 (fill). This round tests 3KB bursts with
//    zero added traffic.
//  - block = 1 wave, panel private -> no barriers; 6 blocks/CU (24KB LDS).
//  - compute: proven 3-slot K/V register rotation, wm from 2x ds_read_b64.
//  keeps: swapped QK^T, no-max softmax (masked -> exactly 0), split-K=3 +
//  plain-sum combine, dual mask-mode kernels, QKV/out projections.

typedef __attribute__((ext_vector_type(8))) short bf16x8;
typedef __attribute__((ext_vector_type(4))) short bf16x4;
typedef __attribute__((ext_vector_type(4))) float f32x4;
typedef __attribute__((ext_vector_type(4))) unsigned int u32x4;

constexpr int B_  = 2;
constexpr int H_  = 8;
constexpr int NQ_ = 2304;
constexpr int DM_ = 64;
constexpr int DK_ = 32;
constexpr int NT_ = NQ_ / 32;     // 72 j-tiles of 32
constexpr int CH_ = 3;            // split-K chunks
constexpr int TPC_ = NT_ / CH_;   // 24 tiles per chunk (768 cols)
constexpr int GT_ = B_ * H_ * (NQ_ / 16);  // 2304 i-tiles
constexpr float SCALE_ = 0.17677669529663687f;  // 1/sqrt(32)

// ws layout (bytes)
constexpr size_t OFF_Q    = 0;
constexpr size_t OFF_K    = 2359296;
constexpr size_t OFF_V    = 4718592;
constexpr size_t OFF_OMID = 7077888;
constexpr size_t OFF_FLAG = 11796480;
constexpr size_t OFF_OP   = 11796736;
constexpr size_t OFF_ML   = 25952512;

static __device__ __forceinline__ unsigned short f2bf(float f) {
    unsigned int u = __builtin_bit_cast(unsigned int, f);
    u += 0x7fffu + ((u >> 16) & 1u);          // RNE; inputs here are finite
    return (unsigned short)(u >> 16);
}
static __device__ __forceinline__ float bf2f(short s) {
    return __builtin_bit_cast(float, ((unsigned int)(unsigned short)s) << 16);
}

// ---------------- k0: mask dtype detect ----------------
__global__ void detect_mask_k(const unsigned int* __restrict__ m, int* __restrict__ flag) {
    int t = threadIdx.x;
    unsigned int v = 0;
    for (int k = 0; k < 16; ++k) v |= m[t * 16 + k];
    unsigned long long b = __ballot(v > 1u);
    if (t == 0) *flag = (b != 0ull) ? 1 : 0;   // 1 => byte-packed bools
}

// ---------------- k1: QKV projections ----------------
__global__ __launch_bounds__(256) void proj_qkv_k(
    const float* __restrict__ qin, const float* __restrict__ kin, const float* __restrict__ vin,
    const float* __restrict__ Wq, const float* __restrict__ bq,
    const float* __restrict__ Wk, const float* __restrict__ bk,
    const float* __restrict__ Wv, const float* __restrict__ bv,
    unsigned short* __restrict__ Qbf, unsigned short* __restrict__ Kbf,
    unsigned short* __restrict__ Vbf)
{
    const int sel = blockIdx.y;
    const float* in  = sel == 0 ? qin : (sel == 1 ? kin : vin);
    const float* W   = sel == 0 ? Wq  : (sel == 1 ? Wk  : Wv);
    const float* bia = sel == 0 ? bq  : (sel == 1 ? bk  : bv);

    const int rt = blockIdx.x;
    const int b  = rt / (NQ_ / 8);
    const int r0 = (rt % (NQ_ / 8)) * 8;

    __shared__ alignas(16) float ins[8][64];
    const int t = threadIdx.x;
    const float4* src = reinterpret_cast<const float4*>(in + ((size_t)b * NQ_ + r0) * DM_);
    if (t < 128) reinterpret_cast<float4*>(&ins[0][0])[t] = src[t];
    __syncthreads();

    float acc[8];
#pragma unroll
    for (int r = 0; r < 8; ++r) acc[r] = 0.f;
    const float* wrow = W + t * DM_;
    for (int m = 0; m < DM_; ++m) {
        float wv = wrow[m];
#pragma unroll
        for (int r = 0; r < 8; ++r) acc[r] += ins[r][m] * wv;
    }
    const float bb = bia[t];
    const int h = t >> 5, d = t & 31;
#pragma unroll
    for (int r = 0; r < 8; ++r) {
        float o = acc[r] + bb;
        if (sel == 0) o *= SCALE_;             // fold 1/sqrt(dk) into Q
        unsigned short bvv = f2bf(o);
        if (sel == 2) Vbf[(((size_t)b * H_ + h) * DK_ + d) * NQ_ + (r0 + r)] = bvv;
        else {
            unsigned short* out = (sel == 1) ? Kbf : Qbf;
            out[(((size_t)b * H_ + h) * NQ_ + (r0 + r)) * DK_ + d] = bvv;
        }
    }
}

// ---------------- k2: flash attention (3KB-burst panel staging) ----------------
struct KVSlot {
    bf16x8 ka0, ka1;
    bf16x4 v00, v01, v10, v11;
};

static __device__ __forceinline__ void issue_kv(KVSlot& s,
    const unsigned short* __restrict__ kbase, const unsigned short* __restrict__ vbase,
    int j0, int l15, int hi)
{
    s.ka0 = *reinterpret_cast<const bf16x8*>(kbase + (size_t)(j0 + l15) * DK_ + 8 * hi);
    s.ka1 = *reinterpret_cast<const bf16x8*>(kbase + (size_t)(j0 + 16 + l15) * DK_ + 8 * hi);
    s.v00 = *reinterpret_cast<const bf16x4*>(vbase + (size_t)l15 * NQ_ + j0 + 4 * hi);
    s.v01 = *reinterpret_cast<const bf16x4*>(vbase + (size_t)l15 * NQ_ + j0 + 16 + 4 * hi);
    s.v10 = *reinterpret_cast<const bf16x4*>(vbase + (size_t)(16 + l15) * NQ_ + j0 + 4 * hi);
    s.v11 = *reinterpret_cast<const bf16x4*>(vbase + (size_t)(16 + l15) * NQ_ + j0 + 16 + 4 * hi);
}

static __device__ __forceinline__ void consume_tile(
    const KVSlot& s, bf16x4 wq0, bf16x4 wq1, bf16x8 qb,
    f32x4& oacc0, f32x4& oacc1, float& lrun)
{
    const f32x4 zero = {0.f, 0.f, 0.f, 0.f};
    f32x4 s0 = __builtin_amdgcn_mfma_f32_16x16x32_bf16(s.ka0, qb, zero, 0, 0, 0);
    f32x4 s1 = __builtin_amdgcn_mfma_f32_16x16x32_bf16(s.ka1, qb, zero, 0, 0, 0);

    float p0[4], p1[4];
#pragma unroll
    for (int r = 0; r < 4; ++r) {
        float w0f = bf2f(wq0[r]);
        float w1f = bf2f(wq1[r]);
        float e0 = __expf(s0[r] * w0f);
        float e1 = __expf(s1[r] * w1f);
        p0[r] = (w0f < 0.f) ? 0.f : e0;        // masked encoded as bf16 -1.0
        p1[r] = (w1f < 0.f) ? 0.f : e1;
    }
    lrun += ((p0[0] + p0[1]) + (p0[2] + p0[3])) + ((p1[0] + p1[1]) + (p1[2] + p1[3]));

    bf16x8 pa;
#pragma unroll
    for (int r = 0; r < 4; ++r) {
        pa[r]     = (short)f2bf(p0[r]);
        pa[4 + r] = (short)f2bf(p1[r]);
    }
    bf16x8 vb0 = __builtin_shufflevector(s.v00, s.v01, 0, 1, 2, 3, 4, 5, 6, 7);
    bf16x8 vb1 = __builtin_shufflevector(s.v10, s.v11, 0, 1, 2, 3, 4, 5, 6, 7);
    oacc0 = __builtin_amdgcn_mfma_f32_16x16x32_bf16(pa, vb0, oacc0, 0, 0, 0);
    oacc1 = __builtin_amdgcn_mfma_f32_16x16x32_bf16(pa, vb1, oacc1, 0, 0, 0);
}

template<bool ISBYTE>
static __device__ __forceinline__ void attn_body(
    const unsigned short* __restrict__ Qbf,
    const unsigned short* __restrict__ Kbf,
    const unsigned short* __restrict__ Vbf,
    const float* __restrict__ attw,
    const unsigned char* __restrict__ maskb,
    const int* __restrict__ flagp,
    float* __restrict__ Opart,
    float* __restrict__ MLpart,
    char* panel)
{
    if (((*flagp) != 0) != ISBYTE) return;

    const int lane = threadIdx.x;
    const int l15 = lane & 15, hi = lane >> 4;
    const int g = blockIdx.x;                  // i-tile id 0..2303
    const int chunk = blockIdx.y;
    const int bh = g / (NQ_ / 16);
    const int it = g % (NQ_ / 16);
    const int i0 = it * 16;

    const unsigned short* qbase = Qbf + (size_t)bh * NQ_ * DK_;
    const unsigned short* kbase = Kbf + (size_t)bh * NQ_ * DK_;
    const unsigned short* vbase = Vbf + (size_t)bh * DK_ * NQ_;

    const int q = i0 + l15;
    bf16x8 qb = *reinterpret_cast<const bf16x8*>(qbase + (size_t)q * DK_ + 8 * hi);

    // ---- stage chunk-panel: 16 rows x 768 cols, 3KB sequential per row per array
    const size_t rowbase = (size_t)(bh * NQ_ + i0) * NQ_ + chunk * 768;
    const float* wsrc = attw + rowbase;

#pragma unroll
    for (int bt = 0; bt < 4; ++bt) {
        f32x4 wv[4][3];
#pragma unroll
        for (int rr = 0; rr < 4; ++rr) {
            const int row = bt * 4 + rr;
#pragma unroll
            for (int s = 0; s < 3; ++s)
                wv[rr][s] = *reinterpret_cast<const f32x4*>(
                    wsrc + (size_t)row * NQ_ + s * 256 + 4 * lane);
        }
        u32x4 mv[4][3];
        unsigned int mvb[4][3];
        if constexpr (ISBYTE) {
            const unsigned char* msrc = maskb + rowbase;
#pragma unroll
            for (int rr = 0; rr < 4; ++rr) {
                const int row = bt * 4 + rr;
#pragma unroll
                for (int s = 0; s < 3; ++s)
                    mvb[rr][s] = *reinterpret_cast<const unsigned int*>(
                        msrc + (size_t)row * NQ_ + s * 256 + 4 * lane);
            }
        } else {
            const int* msrc = (const int*)maskb + rowbase;
#pragma unroll
            for (int rr = 0; rr < 4; ++rr) {
                const int row = bt * 4 + rr;
#pragma unroll
                for (int s = 0; s < 3; ++s)
                    mv[rr][s] = *reinterpret_cast<const u32x4*>(
                        msrc + (size_t)row * NQ_ + s * 256 + 4 * lane);
            }
        }
#pragma unroll
        for (int rr = 0; rr < 4; ++rr) {
            const int row = bt * 4 + rr;
#pragma unroll
            for (int s = 0; s < 3; ++s) {
                bf16x4 o;
#pragma unroll
                for (int k = 0; k < 4; ++k) {
                    bool msk;
                    if constexpr (ISBYTE) msk = ((mvb[rr][s] >> (8 * k)) & 0xffu) != 0;
                    else                  msk = mv[rr][s][k] != 0;
                    o[k] = msk ? (short)0xBF80 : (short)f2bf(wv[rr][s][k]);
                }
                const int off = (row * 1536 + (s * 256 + 4 * lane) * 2) ^ ((row & 7) << 4);
                *reinterpret_cast<bf16x4*>(panel + off) = o;
            }
        }
    }
    // single wave: compiler inserts lgkmcnt for ds_write->ds_read deps; no barrier.

    // ---- compute: 3-slot K/V rotation over the 24 tiles ----
    const int jb = chunk * 768;
    f32x4 oacc0 = {0.f, 0.f, 0.f, 0.f}, oacc1 = {0.f, 0.f, 0.f, 0.f};
    float lrun = 0.f;

    KVSlot sl0, sl1, sl2;
    issue_kv(sl0, kbase, vbase, jb, l15, hi);
    issue_kv(sl1, kbase, vbase, jb + 32, l15, hi);
    issue_kv(sl2, kbase, vbase, jb + 64, l15, hi);

    const int rb = l15 * 1536;
    const int sw = (l15 & 7) << 4;

    for (int u = 0; u < TPC_; u += 3) {
        {
            bf16x4 wq0 = *reinterpret_cast<const bf16x4*>(panel + ((rb + (u * 32 + 4 * hi) * 2) ^ sw));
            bf16x4 wq1 = *reinterpret_cast<const bf16x4*>(panel + ((rb + (u * 32 + 16 + 4 * hi) * 2) ^ sw));
            consume_tile(sl0, wq0, wq1, qb, oacc0, oacc1, lrun);
            if (u + 3 < TPC_) issue_kv(sl0, kbase, vbase, jb + (u + 3) * 32, l15, hi);
        }
        {
            bf16x4 wq0 = *reinterpret_cast<const bf16x4*>(panel + ((rb + ((u + 1) * 32 + 4 * hi) * 2) ^ sw));
            bf16x4 wq1 = *reinterpret_cast<const bf16x4*>(panel + ((rb + ((u + 1) * 32 + 16 + 4 * hi) * 2) ^ sw));
            consume_tile(sl1, wq0, wq1, qb, oacc0, oacc1, lrun);
            if (u + 4 < TPC_) issue_kv(sl1, kbase, vbase, jb + (u + 4) * 32, l15, hi);
        }
        {
            bf16x4 wq0 = *reinterpret_cast<const bf16x4*>(panel + ((rb + ((u + 2) * 32 + 4 * hi) * 2) ^ sw));
            bf16x4 wq1 = *reinterpret_cast<const bf16x4*>(panel + ((rb + ((u + 2) * 32 + 16 + 4 * hi) * 2) ^ sw));
            consume_tile(sl2, wq0, wq1, qb, oacc0, oacc1, lrun);
            if (u + 5 < TPC_) issue_kv(sl2, kbase, vbase, jb + (u + 5) * 32, l15, hi);
        }
    }

    float* op = Opart + ((size_t)chunk * GT_ + g) * 512;
#pragma unroll
    for (int r = 0; r < 4; ++r) {
        op[(4 * hi + r) * 32 + l15]      = oacc0[r];
        op[(4 * hi + r) * 32 + 16 + l15] = oacc1[r];
    }
    lrun += __shfl_xor(lrun, 16, 64);
    lrun += __shfl_xor(lrun, 32, 64);
    if (hi == 0) {
        float* mlp = MLpart + ((size_t)chunk * GT_ + g) * 32;
        mlp[l15] = lrun;
    }
}

__global__ __launch_bounds__(64) void attn_byte_k(
    const unsigned short* __restrict__ Qbf, const unsigned short* __restrict__ Kbf,
    const unsigned short* __restrict__ Vbf, const float* __restrict__ attw,
    const unsigned char* __restrict__ maskb, const int* __restrict__ flagp,
    float* __restrict__ Opart, float* __restrict__ MLpart)
{
    __shared__ alignas(16) char panel[24576];
    attn_body<true>(Qbf, Kbf, Vbf, attw, maskb, flagp, Opart, MLpart, panel);
}

__global__ __launch_bounds__(64) void attn_int_k(
    const unsigned short* __restrict__ Qbf, const unsigned short* __restrict__ Kbf,
    const unsigned short* __restrict__ Vbf, const float* __restrict__ attw,
    const unsigned char* __restrict__ maskb, const int* __restrict__ flagp,
    float* __restrict__ Opart, float* __restrict__ MLpart)
{
    __shared__ alignas(16) char panel[24576];
    attn_body<false>(Qbf, Kbf, Vbf, attw, maskb, flagp, Opart, MLpart, panel);
}

// ---------------- k2b: combine split-K partials (plain sum) ----------------
__global__ __launch_bounds__(64) void combine_k(
    const float* __restrict__ Opart, const float* __restrict__ MLpart,
    float* __restrict__ Omid)
{
    const int g = blockIdx.x;
    const int lane = threadIdx.x;
    const int row = lane >> 2;
    const int c4  = (lane & 3) * 8;
    const int bh = g / (NQ_ / 16);
    const int it = g % (NQ_ / 16);
    const int b = bh / H_, h = bh % H_;

    float lg = 0.f;
#pragma unroll
    for (int c = 0; c < CH_; ++c)
        lg += MLpart[((size_t)c * GT_ + g) * 32 + row];
    float inv = 1.0f / lg;

    const size_t ob = (size_t)row * 32 + c4;
    f32x4 a0 = {0.f,0.f,0.f,0.f}, a1 = {0.f,0.f,0.f,0.f};
#pragma unroll
    for (int c = 0; c < CH_; ++c) {
        const float* opp = Opart + ((size_t)c * GT_ + g) * 512 + ob;
        a0 += *reinterpret_cast<const f32x4*>(opp);
        a1 += *reinterpret_cast<const f32x4*>(opp + 4);
    }
    a0 *= inv; a1 *= inv;
    float* dst = Omid + ((size_t)b * NQ_ + it * 16 + row) * 256 + h * 32 + c4;
    *reinterpret_cast<f32x4*>(dst)     = a0;
    *reinterpret_cast<f32x4*>(dst + 4) = a1;
}

// ---------------- k3: output projection ----------------
__global__ __launch_bounds__(256) void proj_out_k(
    const float* __restrict__ Omid, const float* __restrict__ Wo,
    const float* __restrict__ bo, float* __restrict__ out)
{
    const int rt = blockIdx.x;
    const int b  = rt / (NQ_ / 16);
    const int r0 = (rt % (NQ_ / 16)) * 16;

    __shared__ alignas(16) float lds[16][256];
    const int t = threadIdx.x;
    const float4* src = reinterpret_cast<const float4*>(Omid + ((size_t)b * NQ_ + r0) * 256);
#pragma unroll
    for (int k = 0; k < 4; ++k) reinterpret_cast<float4*>(&lds[0][0])[t + k * 256] = src[t + k * 256];
    __syncthreads();

    const int m = t & 63, rg = t >> 6;
    float acc[4] = {0.f, 0.f, 0.f, 0.f};
    const float* wrow = Wo + m * 256;
    for (int c = 0; c < 256; ++c) {
        float wv = wrow[c];
#pragma unroll
        for (int rr = 0; rr < 4; ++rr) acc[rr] += lds[rg * 4 + rr][c] * wv;
    }
    const float bb = bo[m];
#pragma unroll
    for (int rr = 0; rr < 4; ++rr)
        out[((size_t)b * NQ_ + r0 + rg * 4 + rr) * 64 + m] = acc[rr] + bb;
}

extern "C" void kernel_launch(void* const* d_in, const int* in_sizes, int n_in,
                              void* d_out, int out_size, void* d_ws, size_t ws_size,
                              hipStream_t stream)
{
    (void)in_sizes; (void)n_in; (void)out_size; (void)ws_size;
    const float* qin  = (const float*)d_in[0];
    const float* kin  = (const float*)d_in[1];
    const float* vin  = (const float*)d_in[2];
    const float* attw = (const float*)d_in[3];
    const void*  mask = d_in[4];
    const float* Wq = (const float*)d_in[5];
    const float* bq = (const float*)d_in[6];
    const float* Wk = (const float*)d_in[7];
    const float* bk = (const float*)d_in[8];
    const float* Wv = (const float*)d_in[9];
    const float* bv = (const float*)d_in[10];
    const float* Wo = (const float*)d_in[11];
    const float* bo = (const float*)d_in[12];

    char* ws = (char*)d_ws;
    unsigned short* Qbf   = (unsigned short*)(ws + OFF_Q);
    unsigned short* Kbf   = (unsigned short*)(ws + OFF_K);
    unsigned short* Vbf   = (unsigned short*)(ws + OFF_V);
    float*          Omid  = (float*)(ws + OFF_OMID);
    int*            flag  = (int*)(ws + OFF_FLAG);
    float*          Opart = (float*)(ws + OFF_OP);
    float*          MLp   = (float*)(ws + OFF_ML);

    detect_mask_k<<<1, 64, 0, stream>>>((const unsigned int*)mask, flag);
    proj_qkv_k<<<dim3(B_ * NQ_ / 8, 3), 256, 0, stream>>>(
        qin, kin, vin, Wq, bq, Wk, bk, Wv, bv, Qbf, Kbf, Vbf);
    attn_byte_k<<<dim3(GT_, CH_), 64, 0, stream>>>(
        Qbf, Kbf, Vbf, attw, (const unsigned char*)mask, flag, Opart, MLp);
    attn_int_k<<<dim3(GT_, CH_), 64, 0, stream>>>(
        Qbf, Kbf, Vbf, attw, (const unsigned char*)mask, flag, Opart, MLp);
    combine_k<<<GT_, 64, 0, stream>>>(Opart, MLp, Omid);
    proj_out_k<<<B_ * NQ_ / 16, 256, 0, stream>>>(Omid, Wo, bo, (float*)d_out);
}

// Round 9
// 218.222 us; speedup vs baseline: 1.6604x; 1.1516x over previous
//
#include <hip/hip_runtime.h>

// R9 = R6 restored (best measured: 217.7 us total, attn 209 us).
// Rationale: eight rounds establish a ~3.2-3.3 TB/s delivered READ ceiling on
// this part (R2-R8 all converge there; "6.3 TB/s" corpus figure is a copy =
// read+write summed). attn's compulsory read = 680 MB (W f32 + mask int32,
// each byte read exactly once per dispatch) -> floor ~209 us; R6 measured
// exactly that. R7 (prepack) and R8 (3KB bursts) both regressed; R6 is the
// roofline kernel.
//  - attn: all loop streams staged to LDS via global_load_lds in private
//    per-wave double-buffered 8KB slots, counted s_waitcnt vmcnt(8).
//  - XOR-swizzled LDS (pre-swizzled global sources, swizzled reads).
//  - 192-thread blocks (3 waves), 48KB LDS, no barriers, wave-private slots.
//  - swapped QK^T, no-max softmax (masked -> exactly 0), split-K=3 +
//    plain-sum combine, dual mask-mode kernels.

typedef __attribute__((ext_vector_type(8))) short bf16x8;
typedef __attribute__((ext_vector_type(4))) short bf16x4;
typedef __attribute__((ext_vector_type(4))) float f32x4;
typedef __attribute__((ext_vector_type(4))) unsigned int u32x4;

constexpr int B_  = 2;
constexpr int H_  = 8;
constexpr int NQ_ = 2304;
constexpr int DM_ = 64;
constexpr int DK_ = 32;
constexpr int NT_ = NQ_ / 32;     // 72 j-tiles of 32
constexpr int CH_ = 3;            // split-K chunks
constexpr int TPC_ = NT_ / CH_;   // 24 tiles per chunk
constexpr int GT_ = B_ * H_ * (NQ_ / 16);  // 2304 i-tiles total
constexpr float SCALE_ = 0.17677669529663687f;  // 1/sqrt(32)

// ws layout (bytes)
constexpr size_t OFF_Q    = 0;
constexpr size_t OFF_K    = 2359296;
constexpr size_t OFF_V    = 4718592;
constexpr size_t OFF_OMID = 7077888;    // 2*2304*256 f32
constexpr size_t OFF_FLAG = 11796480;
constexpr size_t OFF_OP   = 11796736;   // CH*2304*512 f32
constexpr size_t OFF_ML   = 25952512;   // CH*2304*32  f32

static __device__ __forceinline__ unsigned short f2bf(float f) {
    unsigned int u = __builtin_bit_cast(unsigned int, f);
    u += 0x7fffu + ((u >> 16) & 1u);          // RNE; inputs here are finite
    return (unsigned short)(u >> 16);
}

// async global->LDS, 16B per lane. dst must be wave-uniform base (+lane*16 HW).
#define GLL16(SRC, DST) __builtin_amdgcn_global_load_lds( \
    (const __attribute__((address_space(1))) unsigned int*)(const void*)(SRC), \
    (__attribute__((address_space(3))) unsigned int*)(void*)(DST), 16, 0, 0)

// ---------------- k0: mask dtype detect ----------------
__global__ void detect_mask_k(const unsigned int* __restrict__ m, int* __restrict__ flag) {
    int t = threadIdx.x;                       // 64 threads, 1 wave
    unsigned int v = 0;
    for (int k = 0; k < 16; ++k) v |= m[t * 16 + k];   // first 4KB, safe in both modes
    unsigned long long b = __ballot(v > 1u);
    if (t == 0) *flag = (b != 0ull) ? 1 : 0;   // 1 => byte-packed bools
}

// ---------------- k1: QKV projections ----------------
__global__ __launch_bounds__(256) void proj_qkv_k(
    const float* __restrict__ qin, const float* __restrict__ kin, const float* __restrict__ vin,
    const float* __restrict__ Wq, const float* __restrict__ bq,
    const float* __restrict__ Wk, const float* __restrict__ bk,
    const float* __restrict__ Wv, const float* __restrict__ bv,
    unsigned short* __restrict__ Qbf, unsigned short* __restrict__ Kbf,
    unsigned short* __restrict__ Vbf)
{
    const int sel = blockIdx.y;
    const float* in  = sel == 0 ? qin : (sel == 1 ? kin : vin);
    const float* W   = sel == 0 ? Wq  : (sel == 1 ? Wk  : Wv);
    const float* bia = sel == 0 ? bq  : (sel == 1 ? bk  : bv);

    const int rt = blockIdx.x;                 // 0..(B*NQ/8-1)
    const int b  = rt / (NQ_ / 8);
    const int r0 = (rt % (NQ_ / 8)) * 8;

    __shared__ alignas(16) float ins[8][64];
    const int t = threadIdx.x;
    const float4* src = reinterpret_cast<const float4*>(in + ((size_t)b * NQ_ + r0) * DM_);
    if (t < 128) reinterpret_cast<float4*>(&ins[0][0])[t] = src[t];
    __syncthreads();

    float acc[8];
#pragma unroll
    for (int r = 0; r < 8; ++r) acc[r] = 0.f;
    const float* wrow = W + t * DM_;
    for (int m = 0; m < DM_; ++m) {
        float wv = wrow[m];
#pragma unroll
        for (int r = 0; r < 8; ++r) acc[r] += ins[r][m] * wv;
    }
    const float bb = bia[t];
    const int h = t >> 5, d = t & 31;
#pragma unroll
    for (int r = 0; r < 8; ++r) {
        float o = acc[r] + bb;
        if (sel == 0) o *= SCALE_;             // fold 1/sqrt(dk) into Q
        unsigned short bvv = f2bf(o);
        if (sel == 2) Vbf[(((size_t)b * H_ + h) * DK_ + d) * NQ_ + (r0 + r)] = bvv;
        else {
            unsigned short* out = (sel == 1) ? Kbf : Qbf;
            out[(((size_t)b * H_ + h) * NQ_ + (r0 + r)) * DK_ + d] = bvv;
        }
    }
}

// ---------------- k2: flash attention (LDS-staged deep pipeline) ----------------
// LDS slot layout per wave (8192 B x 2 slots):
//   +0    : W  16 rows x 32 f32, row 128B, quad-swizzled  (phys_quad = log ^ (row&7))
//   +2048 : M  (int mode) same geometry as W
//   +4096 : K  32 rows x 32 bf16, row 64B, chunk-swizzled (phys = log ^ ((row>>1)&3))
//   +6144 : V  32 dv   x 32 bf16, same swizzle as K

struct Frag {
    f32x4 w0, w1;
    u32x4 m0, m1;
    bf16x8 ka0, ka1;
    bf16x4 v00, v01, v10, v11;
};

template<bool ISBYTE>
static __device__ __forceinline__ void attn_body(
    const unsigned short* __restrict__ Qbf,
    const unsigned short* __restrict__ Kbf,
    const unsigned short* __restrict__ Vbf,
    const float* __restrict__ attw,
    const unsigned char* __restrict__ maskb,
    const int* __restrict__ flagp,
    float* __restrict__ Opart,
    float* __restrict__ MLpart,
    char* lds)
{
    if (((*flagp) != 0) != ISBYTE) return;     // wrong-mode instance: cheap no-op

    const int tid = threadIdx.x;
    const int wid = tid >> 6, lane = tid & 63;
    const int l15 = lane & 15, hi = lane >> 4;
    const int g = blockIdx.x * 3 + wid;        // global i-tile id 0..2303
    const int chunk = blockIdx.y;
    const int bh = g / (NQ_ / 16);
    const int it = g % (NQ_ / 16);
    const int i0 = it * 16;
    const int q = i0 + l15;                    // this lane's q-row

    const unsigned short* qbase = Qbf + (size_t)bh * NQ_ * DK_;
    const unsigned short* kbase = Kbf + (size_t)bh * NQ_ * DK_;
    const unsigned short* vbase = Vbf + (size_t)bh * DK_ * NQ_;
    const float* wbase = attw + (size_t)bh * NQ_ * NQ_;

    bf16x8 qb = *reinterpret_cast<const bf16x8*>(qbase + (size_t)q * DK_ + 8 * hi);

    // ---- per-lane stage-source geometry (pre-swizzled so LDS dest is linear) ----
    const int r8 = lane >> 3, q8 = lane & 7;           // W/M: 8 rows x 8 quads per instr
    const int wq = (q8 ^ r8) * 4;                      // logical f32/i32 col offset
    const float* pW0 = wbase + (size_t)(i0 + r8) * NQ_ + wq;
    const float* pW1 = pW0 + (size_t)8 * NQ_;
    const int* pM0 = (const int*)maskb + (size_t)(bh * NQ_ + i0 + r8) * NQ_ + wq;
    const int* pM1 = pM0 + (size_t)8 * NQ_;
    const int r4 = lane >> 2, q4 = lane & 3;           // K/V: 16 rows x 4 chunks per instr
    const int kq = (q4 ^ ((r4 >> 1) & 3)) * 8;         // logical bf16 col offset
    const unsigned short* pK0 = kbase + (size_t)r4 * DK_ + kq;
    const unsigned short* pK1 = pK0 + (size_t)16 * DK_;
    const unsigned short* pV0 = vbase + (size_t)r4 * NQ_ + kq;
    const unsigned short* pV1 = pV0 + (size_t)16 * NQ_;

    const unsigned char* mrow = maskb + ((size_t)bh * NQ_ + q) * NQ_;  // byte mode

    char* sb0 = lds + wid * 16384;
    char* sb1 = sb0 + 8192;

    auto stage = [&](char* sb, int tile) {
        const int j0 = tile * 32;
        GLL16(pW0 + j0, sb);
        GLL16(pW1 + j0, sb + 1024);
        if constexpr (!ISBYTE) {
            GLL16(pM0 + j0, sb + 2048);
            GLL16(pM1 + j0, sb + 3072);
        }
        GLL16(pK0 + (size_t)j0 * DK_, sb + 4096);
        GLL16(pK1 + (size_t)j0 * DK_, sb + 5120);
        GLL16(pV0 + j0, sb + 6144);
        GLL16(pV1 + j0, sb + 7168);
    };

    auto load_frag = [&](const char* sb, Frag& f) {
        const int qA = (hi ^ (l15 & 7)) << 4;
        const int qB = ((hi + 4) ^ (l15 & 7)) << 4;
        const int rw = l15 << 7;
        f.w0 = *(const f32x4*)(sb + rw + qA);
        f.w1 = *(const f32x4*)(sb + rw + qB);
        if constexpr (!ISBYTE) {
            f.m0 = *(const u32x4*)(sb + 2048 + rw + qA);
            f.m1 = *(const u32x4*)(sb + 2048 + rw + qB);
        }
        const int kc = (hi ^ ((l15 >> 1) & 3)) << 4;
        f.ka0 = *(const bf16x8*)(sb + 4096 + (l15 << 6) + kc);
        f.ka1 = *(const bf16x8*)(sb + 4096 + ((16 + l15) << 6) + kc);
        const int vh = (hi & 1) << 3;
        const int vc0 = ((((hi >> 1)) ^ ((l15 >> 1) & 3)) << 4) + vh;
        const int vc1 = (((2 + (hi >> 1)) ^ ((l15 >> 1) & 3)) << 4) + vh;
        f.v00 = *(const bf16x4*)(sb + 6144 + (l15 << 6) + vc0);
        f.v01 = *(const bf16x4*)(sb + 6144 + (l15 << 6) + vc1);
        f.v10 = *(const bf16x4*)(sb + 6144 + ((16 + l15) << 6) + vc0);
        f.v11 = *(const bf16x4*)(sb + 6144 + ((16 + l15) << 6) + vc1);
    };

    f32x4 oacc0 = {0.f, 0.f, 0.f, 0.f}, oacc1 = {0.f, 0.f, 0.f, 0.f};
    float lrun = 0.f;

    auto compute_frag = [&](const Frag& f, unsigned int mba, unsigned int mbb) {
        const f32x4 zero = {0.f, 0.f, 0.f, 0.f};
        f32x4 s0 = __builtin_amdgcn_mfma_f32_16x16x32_bf16(f.ka0, qb, zero, 0, 0, 0);
        f32x4 s1 = __builtin_amdgcn_mfma_f32_16x16x32_bf16(f.ka1, qb, zero, 0, 0, 0);
        float p0[4], p1[4];
#pragma unroll
        for (int r = 0; r < 4; ++r) {
            float e0 = __expf(s0[r] * f.w0[r]);
            float e1 = __expf(s1[r] * f.w1[r]);
            bool k0, k1;
            if constexpr (ISBYTE) {
                k0 = ((mba >> (8 * r)) & 0xffu) != 0;
                k1 = ((mbb >> (8 * r)) & 0xffu) != 0;
            } else {
                k0 = f.m0[r] != 0;
                k1 = f.m1[r] != 0;
            }
            p0[r] = k0 ? 0.f : e0;
            p1[r] = k1 ? 0.f : e1;
        }
        lrun += ((p0[0] + p0[1]) + (p0[2] + p0[3])) + ((p1[0] + p1[1]) + (p1[2] + p1[3]));
        bf16x8 pa;
#pragma unroll
        for (int r = 0; r < 4; ++r) {
            pa[r]     = (short)f2bf(p0[r]);
            pa[4 + r] = (short)f2bf(p1[r]);
        }
        bf16x8 vb0 = __builtin_shufflevector(f.v00, f.v01, 0, 1, 2, 3, 4, 5, 6, 7);
        bf16x8 vb1 = __builtin_shufflevector(f.v10, f.v11, 0, 1, 2, 3, 4, 5, 6, 7);
        oacc0 = __builtin_amdgcn_mfma_f32_16x16x32_bf16(pa, vb0, oacc0, 0, 0, 0);
        oacc1 = __builtin_amdgcn_mfma_f32_16x16x32_bf16(pa, vb1, oacc1, 0, 0, 0);
    };

    const int t0 = chunk * TPC_, t1 = t0 + TPC_;

    stage(sb0, t0);
    stage(sb1, t0 + 1);
    int cur = 0;

    for (int u = t0; u < t1 - 1; ++u) {
        char* sbc = cur ? sb1 : sb0;
        // wait for tile u's stages (oldest 8/6), keep tile u+1's in flight
        if constexpr (ISBYTE) asm volatile("s_waitcnt vmcnt(6)" ::: "memory");
        else                  asm volatile("s_waitcnt vmcnt(8)" ::: "memory");
        Frag f;
        load_frag(sbc, f);
        unsigned int mba = 0, mbb = 0;
        if constexpr (ISBYTE) {
            mba = *(const unsigned int*)(mrow + u * 32 + 4 * hi);
            mbb = *(const unsigned int*)(mrow + u * 32 + 16 + 4 * hi);
        }
        // fence: ds_reads complete before this slot is re-staged (same wave)
        asm volatile("s_waitcnt lgkmcnt(0)" ::: "memory");
        if (u + 2 < t1) stage(sbc, u + 2);
        compute_frag(f, mba, mbb);
        cur ^= 1;
    }
    {   // peeled last tile: drain
        char* sbc = cur ? sb1 : sb0;
        asm volatile("s_waitcnt vmcnt(0)" ::: "memory");
        Frag f;
        load_frag(sbc, f);
        unsigned int mba = 0, mbb = 0;
        if constexpr (ISBYTE) {
            mba = *(const unsigned int*)(mrow + (t1 - 1) * 32 + 4 * hi);
            mbb = *(const unsigned int*)(mrow + (t1 - 1) * 32 + 16 + 4 * hi);
        }
        asm volatile("s_waitcnt lgkmcnt(0)" ::: "memory");
        compute_frag(f, mba, mbb);
    }

    float* op = Opart + ((size_t)chunk * GT_ + g) * 512;
#pragma unroll
    for (int r = 0; r < 4; ++r) {
        op[(4 * hi + r) * 32 + l15]      = oacc0[r];
        op[(4 * hi + r) * 32 + 16 + l15] = oacc1[r];
    }
    lrun += __shfl_xor(lrun, 16, 64);
    lrun += __shfl_xor(lrun, 32, 64);
    if (hi == 0) {
        float* mlp = MLpart + ((size_t)chunk * GT_ + g) * 32;
        mlp[l15] = lrun;
    }
}

__global__ __launch_bounds__(192) void attn_byte_k(
    const unsigned short* __restrict__ Qbf, const unsigned short* __restrict__ Kbf,
    const unsigned short* __restrict__ Vbf, const float* __restrict__ attw,
    const unsigned char* __restrict__ maskb, const int* __restrict__ flagp,
    float* __restrict__ Opart, float* __restrict__ MLpart)
{
    __shared__ alignas(16) char lds[3 * 2 * 8192];
    attn_body<true>(Qbf, Kbf, Vbf, attw, maskb, flagp, Opart, MLpart, lds);
}

__global__ __launch_bounds__(192) void attn_int_k(
    const unsigned short* __restrict__ Qbf, const unsigned short* __restrict__ Kbf,
    const unsigned short* __restrict__ Vbf, const float* __restrict__ attw,
    const unsigned char* __restrict__ maskb, const int* __restrict__ flagp,
    float* __restrict__ Opart, float* __restrict__ MLpart)
{
    __shared__ alignas(16) char lds[3 * 2 * 8192];
    attn_body<false>(Qbf, Kbf, Vbf, attw, maskb, flagp, Opart, MLpart, lds);
}

// ---------------- k2b: combine split-K partials (plain sum) ----------------
__global__ __launch_bounds__(64) void combine_k(
    const float* __restrict__ Opart, const float* __restrict__ MLpart,
    float* __restrict__ Omid)
{
    const int g = blockIdx.x;                  // i-tile id
    const int lane = threadIdx.x;
    const int row = lane >> 2;                 // 16 rows
    const int c4  = (lane & 3) * 8;            // 8 dv per lane
    const int bh = g / (NQ_ / 16);
    const int it = g % (NQ_ / 16);
    const int b = bh / H_, h = bh % H_;

    float lg = 0.f;
#pragma unroll
    for (int c = 0; c < CH_; ++c)
        lg += MLpart[((size_t)c * GT_ + g) * 32 + row];
    float inv = 1.0f / lg;

    const size_t ob = (size_t)row * 32 + c4;
    f32x4 a0 = {0.f,0.f,0.f,0.f}, a1 = {0.f,0.f,0.f,0.f};
#pragma unroll
    for (int c = 0; c < CH_; ++c) {
        const float* opp = Opart + ((size_t)c * GT_ + g) * 512 + ob;
        a0 += *reinterpret_cast<const f32x4*>(opp);
        a1 += *reinterpret_cast<const f32x4*>(opp + 4);
    }
    a0 *= inv; a1 *= inv;
    float* dst = Omid + ((size_t)b * NQ_ + it * 16 + row) * 256 + h * 32 + c4;
    *reinterpret_cast<f32x4*>(dst)     = a0;
    *reinterpret_cast<f32x4*>(dst + 4) = a1;
}

// ---------------- k3: output projection ----------------
__global__ __launch_bounds__(256) void proj_out_k(
    const float* __restrict__ Omid, const float* __restrict__ Wo,
    const float* __restrict__ bo, float* __restrict__ out)
{
    const int rt = blockIdx.x;                 // 0..(B*NQ/16-1)
    const int b  = rt / (NQ_ / 16);
    const int r0 = (rt % (NQ_ / 16)) * 16;

    __shared__ alignas(16) float lds[16][256]; // 16KB
    const int t = threadIdx.x;
    const float4* src = reinterpret_cast<const float4*>(Omid + ((size_t)b * NQ_ + r0) * 256);
#pragma unroll
    for (int k = 0; k < 4; ++k) reinterpret_cast<float4*>(&lds[0][0])[t + k * 256] = src[t + k * 256];
    __syncthreads();

    const int m = t & 63, rg = t >> 6;
    float acc[4] = {0.f, 0.f, 0.f, 0.f};
    const float* wrow = Wo + m * 256;
    for (int c = 0; c < 256; ++c) {
        float wv = wrow[c];
#pragma unroll
        for (int rr = 0; rr < 4; ++rr) acc[rr] += lds[rg * 4 + rr][c] * wv;
    }
    const float bb = bo[m];
#pragma unroll
    for (int rr = 0; rr < 4; ++rr)
        out[((size_t)b * NQ_ + r0 + rg * 4 + rr) * 64 + m] = acc[rr] + bb;
}

extern "C" void kernel_launch(void* const* d_in, const int* in_sizes, int n_in,
                              void* d_out, int out_size, void* d_ws, size_t ws_size,
                              hipStream_t stream)
{
    (void)in_sizes; (void)n_in; (void)out_size; (void)ws_size;
    const float* qin  = (const float*)d_in[0];
    const float* kin  = (const float*)d_in[1];
    const float* vin  = (const float*)d_in[2];
    const float* attw = (const float*)d_in[3];
    const void*  mask = d_in[4];
    const float* Wq = (const float*)d_in[5];
    const float* bq = (const float*)d_in[6];
    const float* Wk = (const float*)d_in[7];
    const float* bk = (const float*)d_in[8];
    const float* Wv = (const float*)d_in[9];
    const float* bv = (const float*)d_in[10];
    const float* Wo = (const float*)d_in[11];
    const float* bo = (const float*)d_in[12];

    char* ws = (char*)d_ws;
    unsigned short* Qbf   = (unsigned short*)(ws + OFF_Q);
    unsigned short* Kbf   = (unsigned short*)(ws + OFF_K);
    unsigned short* Vbf   = (unsigned short*)(ws + OFF_V);
    float*          Omid  = (float*)(ws + OFF_OMID);
    int*            flag  = (int*)(ws + OFF_FLAG);
    float*          Opart = (float*)(ws + OFF_OP);
    float*          MLp   = (float*)(ws + OFF_ML);

    detect_mask_k<<<1, 64, 0, stream>>>((const unsigned int*)mask, flag);
    proj_qkv_k<<<dim3(B_ * NQ_ / 8, 3), 256, 0, stream>>>(
        qin, kin, vin, Wq, bq, Wk, bk, Wv, bv, Qbf, Kbf, Vbf);
    attn_byte_k<<<dim3(GT_ / 3, CH_), 192, 0, stream>>>(
        Qbf, Kbf, Vbf, attw, (const unsigned char*)mask, flag, Opart, MLp);
    attn_int_k<<<dim3(GT_ / 3, CH_), 192, 0, stream>>>(
        Qbf, Kbf, Vbf, attw, (const unsigned char*)mask, flag, Opart, MLp);
    combine_k<<<GT_, 64, 0, stream>>>(Opart, MLp, Omid);
    proj_out_k<<<B_ * NQ_ / 16, 256, 0, stream>>>(Omid, Wo, bo, (float*)d_out);
}